// Round 2
// baseline (324.457 us; speedup 1.0000x reference)
//
#include <hip/hip_runtime.h>
#include <stdint.h>
#include <stddef.h>

#define NN 8192
#define FD 512
#define ATTN_OFF (NN * FD)

typedef __attribute__((ext_vector_type(8))) short bf16x8;
typedef __attribute__((ext_vector_type(4))) float f32x4;
typedef __attribute__((ext_vector_type(4))) int i32x4;
typedef __attribute__((ext_vector_type(2))) uint32_t u32x2;
typedef __attribute__((ext_vector_type(4))) uint32_t u32x4;
typedef __attribute__((ext_vector_type(4))) uint16_t u16x4;

static __device__ __forceinline__ uint16_t f2bf(float x){
    union { float f; uint32_t u; } v; v.f = x;
    uint32_t r = v.u + 0x7FFFu + ((v.u >> 16) & 1u);
    return (uint16_t)(r >> 16);
}

#define GLDS(gp, lp) \
    __builtin_amdgcn_global_load_lds((__attribute__((address_space(1))) void*)(gp), \
                                     (__attribute__((address_space(3))) void*)(lp), 16, 0, 0)

// ---------------- u = W @ a1, v = W @ a2  (contract over OUT_F axis n) ---------------
// va1[k] = sum_n W[k][n] * a[n];  va2[k] = sum_n W[k][n] * a[OUT_F + n]
__global__ void k_va(const float* __restrict__ W, const float* __restrict__ a,
                     float* __restrict__ va1, float* __restrict__ va2){
    const int lane = threadIdx.x & 63, wave = threadIdx.x >> 6;
    const int k = blockIdx.x*8 + wave;           // grid 64 x block 512 -> 512 rows
    const float* wr = W + (size_t)k*FD;
    float s1 = 0.f, s2 = 0.f;
    #pragma unroll
    for (int e = 0; e < 2; ++e){
        int c = e*256 + lane*4;
        f32x4 wv = *(const f32x4*)(wr + c);
        f32x4 x1 = *(const f32x4*)(a + c);
        f32x4 x2 = *(const f32x4*)(a + FD + c);
        s1 += wv[0]*x1[0] + wv[1]*x1[1] + wv[2]*x1[2] + wv[3]*x1[3];
        s2 += wv[0]*x2[0] + wv[1]*x2[1] + wv[2]*x2[2] + wv[3]*x2[3];
    }
    for (int off = 32; off; off >>= 1){ s1 += __shfl_down(s1, off); s2 += __shfl_down(s2, off); }
    if (lane == 0){ va1[k] = s1; va2[k] = s2; }
}

// ---------------- convert h -> bf16, W -> bf16 transposed ----------------------------
__global__ void k_conv(const float* __restrict__ h, const float* __restrict__ W,
                       uint16_t* __restrict__ h_b, uint16_t* __restrict__ WT_b){
    int idx = blockIdx.x * blockDim.x + threadIdx.x;
    int stride = gridDim.x * blockDim.x;
    for (int i = idx; i < NN*FD/4; i += stride){
        f32x4 v = ((const f32x4*)h)[i];
        u16x4 o;
        o[0] = f2bf(v[0]); o[1] = f2bf(v[1]); o[2] = f2bf(v[2]); o[3] = f2bf(v[3]);
        ((u16x4*)h_b)[i] = o;
    }
    for (int i = idx; i < FD*FD; i += stride){
        int n = i >> 9, k = i & 511;
        WT_b[i] = f2bf(W[(size_t)k*FD + n]);   // WT_b[n][k] = W[k][n]
    }
}

// ---------------- per-row s1,s2 and exp tables ---------------------------------------
__global__ void k_rows(const float* __restrict__ h, const float* __restrict__ va1,
                       const float* __restrict__ va2, float* __restrict__ Tarr,
                       float* __restrict__ E1p, float* __restrict__ E1n,
                       float* __restrict__ E2p, float* __restrict__ E2n){
    const int lane = threadIdx.x & 63, wave = threadIdx.x >> 6;
    const int row = blockIdx.x*4 + wave;
    const float* hr = h + (size_t)row * FD;
    float s1 = 0.f, s2 = 0.f;
    #pragma unroll
    for (int e = 0; e < 2; ++e){
        int c = e*256 + lane*4;
        f32x4 hv = *(const f32x4*)(hr + c);
        f32x4 x1 = *(const f32x4*)(va1 + c);
        f32x4 x2 = *(const f32x4*)(va2 + c);
        s1 += hv[0]*x1[0] + hv[1]*x1[1] + hv[2]*x1[2] + hv[3]*x1[3];
        s2 += hv[0]*x2[0] + hv[1]*x2[1] + hv[2]*x2[2] + hv[3]*x2[3];
    }
    for (int off = 32; off; off >>= 1){ s1 += __shfl_down(s1, off); s2 += __shfl_down(s2, off); }
    if (lane == 0){
        Tarr[row] = expf(-s1);        // threshold: x>0  <=>  E2p[j] > T[i]
        E1p[row]  = expf(s1);
        E1n[row]  = expf(0.2f*s1);
        E2p[row]  = expf(s2);
        E2n[row]  = expf(0.2f*s2);
    }
}

// ---------------- pass over adj: softmax denominators + bit-pack ---------------------
// packed word layout: word w (of 256/row), bit b: j = (w>>6)*2048 + (b>>2)*256 + (w&63)*4 + (b&3)
__global__ void k_pack(const int* __restrict__ adj, const float* __restrict__ Tarr,
                       const float* __restrict__ E1p, const float* __restrict__ E1n,
                       const float* __restrict__ E2p, const float* __restrict__ E2n,
                       uint32_t* __restrict__ packed, float* __restrict__ rowP,
                       float* __restrict__ rowN){
    extern __shared__ char smem[];
    float* P_s = (float*)smem;            // 32KB  E2p
    float* Q_s = (float*)(smem + 32768);  // 32KB  E2n
    const int tid = threadIdx.x, lane = tid & 63, wave = tid >> 6;
    for (int t = tid; t < NN/4; t += 256){
        ((f32x4*)P_s)[t] = ((const f32x4*)E2p)[t];
        ((f32x4*)Q_s)[t] = ((const f32x4*)E2n)[t];
    }
    __syncthreads();
    const int row = blockIdx.x*4 + wave;
    const float T_i = Tarr[row];
    const int* arow = adj + (size_t)row * NN;
    float Ap = 0.f, An = 0.f;
    #pragma unroll
    for (int g = 0; g < 4; ++g){
        uint32_t word = 0;
        #pragma unroll
        for (int e = 0; e < 8; ++e){
            int j0 = g*2048 + e*256 + lane*4;
            i32x4 av = *(const i32x4*)(arow + j0);
            f32x4 p = ((const f32x4*)P_s)[j0 >> 2];
            f32x4 q = ((const f32x4*)Q_s)[j0 >> 2];
            #pragma unroll
            for (int c = 0; c < 4; ++c){
                if (av[c] != 0){
                    if (p[c] > T_i) Ap += p[c]; else An += q[c];
                    word |= (1u << (e*4 + c));
                }
            }
        }
        packed[(size_t)row*256 + g*64 + lane] = word;
    }
    for (int off = 32; off; off >>= 1){
        Ap += __shfl_down(Ap, off);
        An += __shfl_down(An, off);
    }
    if (lane == 0){
        float e1p = E1p[row], e1n = E1n[row];
        float inv = 1.0f / (e1p*Ap + e1n*An);
        rowP[row] = e1p * inv;
        rowN[row] = e1n * inv;
    }
}

// ---------------- shared MFMA inner tile (A:[32][64] swz, B:[512][64] swz) -----------
static __device__ __forceinline__ void mfma_tile(const char* A_base, const char* B_base,
                                                 int wave, int lane, f32x4 acc[2][4]){
    #pragma unroll
    for (int kk = 0; kk < 2; ++kk){
        bf16x8 afr[2], bfr[4];
        #pragma unroll
        for (int t = 0; t < 2; ++t){
            int rowl = t*16 + (lane & 15);
            int slot = (kk*4 + (lane >> 4)) ^ (rowl & 7);
            afr[t] = *(const bf16x8*)(A_base + rowl*128 + slot*16);
        }
        #pragma unroll
        for (int n = 0; n < 4; ++n){
            int nl = wave*64 + n*16 + (lane & 15);
            int slot = (kk*4 + (lane >> 4)) ^ (nl & 7);
            bfr[n] = *(const bf16x8*)(B_base + nl*128 + slot*16);
        }
        #pragma unroll
        for (int t = 0; t < 2; ++t)
            #pragma unroll
            for (int n = 0; n < 4; ++n)
                acc[t][n] = __builtin_amdgcn_mfma_f32_16x16x32_bf16(afr[t], bfr[n], acc[t][n], 0, 0, 0);
    }
}

// ---------------- Wh GEMM: WhbT[n][m] = bf16( h[m,:] @ W[:,n] ) ----------------------
__global__ __launch_bounds__(512) void k_wh(const uint16_t* __restrict__ h_b,
                                            const uint16_t* __restrict__ WT_b,
                                            uint16_t* __restrict__ WhbT){
    extern __shared__ char smem[];
    char* A_base = smem;            // 4KB  [32][64] bf16 swz
    char* B_base = smem + 4096;     // 64KB [512][64] bf16 swz; epilogue reuses as Ts
    const int tid = threadIdx.x, wave = tid >> 6, lane = tid & 63;
    const int mb0 = blockIdx.x * 32;
    f32x4 acc[2][4];
    #pragma unroll
    for (int t = 0; t < 2; ++t)
        #pragma unroll
        for (int n = 0; n < 4; ++n) acc[t][n] = (f32x4){0.f,0.f,0.f,0.f};

    for (int k0 = 0; k0 < FD; k0 += 64){
        if (wave < 4){
            int m = wave*8 + (lane >> 3);
            int chunk = (lane & 7) ^ (m & 7);
            GLDS(h_b + (size_t)(mb0 + m)*FD + k0 + chunk*8, A_base + wave*1024);
        }
        #pragma unroll
        for (int r = 0; r < 8; ++r){
            int nn = wave*64 + r*8 + (lane >> 3);
            int chunk = (lane & 7) ^ (nn & 7);
            GLDS(WT_b + (size_t)nn*FD + k0 + chunk*8, B_base + (wave*64 + r*8)*128);
        }
        __syncthreads();
        mfma_tile(A_base, B_base, wave, lane, acc);
        __syncthreads();
    }
    // transpose via LDS: Ts[n][m], row stride 40 shorts (80B, 16B aligned)
    uint16_t* Ts = (uint16_t*)B_base;
    #pragma unroll
    for (int t = 0; t < 2; ++t)
        #pragma unroll
        for (int n = 0; n < 4; ++n)
            #pragma unroll
            for (int r = 0; r < 4; ++r){
                int nl = wave*64 + n*16 + (lane & 15);
                int m  = t*16 + (lane >> 4)*4 + r;
                Ts[nl*40 + m] = f2bf(acc[t][n][r]);
            }
    __syncthreads();
    {
        int n = tid;   // 512 rows
        const u32x4* src = (const u32x4*)(Ts + n*40);
        u32x4* dst = (u32x4*)(WhbT + (size_t)n*NN + mb0);
        #pragma unroll
        for (int r = 0; r < 4; ++r) dst[r] = src[r];
    }
}

// ---------------- fused: attention write + attn @ Wh + ELU ---------------------------
__global__ __launch_bounds__(512) void k_main(const uint32_t* __restrict__ packed,
                                              const uint16_t* __restrict__ WhbT,
                                              const float* __restrict__ Tarr,
                                              const float* __restrict__ rowP,
                                              const float* __restrict__ rowN,
                                              const float* __restrict__ E2p,
                                              const float* __restrict__ E2n,
                                              float* __restrict__ out){
    extern __shared__ char smem[];
    float* E2P_s = (float*)smem;             // 32KB
    float* E2N_s = (float*)(smem + 32768);   // 32KB
    char*  A_base = smem + 65536;            // 4KB  [32][64] bf16 swz
    char*  B_base = smem + 69632;            // 64KB [512][64] bf16 swz   (total 132KB)

    const int tid = threadIdx.x;
    const int il = tid >> 4, jg = tid & 15;
    const int wave = tid >> 6, lane = tid & 63;
    const int row = blockIdx.x * 32 + il;

    for (int t = tid; t < NN/4; t += 512){
        ((f32x4*)E2P_s)[t] = ((const f32x4*)E2p)[t];
        ((f32x4*)E2N_s)[t] = ((const f32x4*)E2n)[t];
    }

    const float T_i = Tarr[row], rP = rowP[row], rN = rowN[row];
    const uint32_t* packrow = packed + (size_t)row * 256;
    float* attn_out = out + ATTN_OFF + (size_t)row * NN;
    char* Bw = B_base + wave * 64 * 128;

    f32x4 acc[2][4];
    #pragma unroll
    for (int t = 0; t < 2; ++t)
        #pragma unroll
        for (int n = 0; n < 4; ++n) acc[t][n] = (f32x4){0.f,0.f,0.f,0.f};

    __syncthreads();   // E2 tables staged

    for (int k0 = 0; k0 < NN; k0 += 64){
        // --- B staging first (latency hides under A generation) ---
        #pragma unroll
        for (int r = 0; r < 8; ++r){
            int nn = wave*64 + r*8 + (lane >> 3);
            int chunk = (lane & 7) ^ (nn & 7);
            GLDS(WhbT + (size_t)nn*NN + k0 + chunk*8, Bw + r*1024);
        }
        // --- A generation: attention tile (fp32 out + bf16 LDS) ---
        uint32_t word = packrow[(k0 >> 11)*64 + ((k0 & 255) >> 2) + jg];
        int shift = ((k0 >> 8) & 7) * 4;
        f32x4 p = ((const f32x4*)E2P_s)[(k0 >> 2) + jg];
        f32x4 q = ((const f32x4*)E2N_s)[(k0 >> 2) + jg];
        float va[4];
        #pragma unroll
        for (int c = 0; c < 4; ++c){
            float val = (p[c] > T_i) ? rP * p[c] : rN * q[c];
            va[c] = ((word >> (shift + c)) & 1u) ? val : 0.f;
        }
        f32x4 st; st[0]=va[0]; st[1]=va[1]; st[2]=va[2]; st[3]=va[3];
        *(f32x4*)(attn_out + k0 + jg*4) = st;
        uint32_t lo = ((uint32_t)f2bf(va[1]) << 16) | f2bf(va[0]);
        uint32_t hi = ((uint32_t)f2bf(va[3]) << 16) | f2bf(va[2]);
        u32x2 pr; pr[0] = lo; pr[1] = hi;
        int abyte = il*128 + ((((jg >> 1) ^ (il & 7)) << 4) | ((jg & 1) << 3));
        *(u32x2*)(A_base + abyte) = pr;
        __syncthreads();
        mfma_tile(A_base, B_base, wave, lane, acc);
        __syncthreads();
    }
    // epilogue: ELU + store h_prime
    #pragma unroll
    for (int t = 0; t < 2; ++t)
        #pragma unroll
        for (int n = 0; n < 4; ++n)
            #pragma unroll
            for (int r = 0; r < 4; ++r){
                int m   = blockIdx.x*32 + t*16 + (lane >> 4)*4 + r;
                int col = wave*64 + n*16 + (lane & 15);
                float x = acc[t][n][r];
                out[(size_t)m*FD + col] = (x > 0.f) ? x : expm1f(x);
            }
}

extern "C" void kernel_launch(void* const* d_in, const int* in_sizes, int n_in,
                              void* d_out, int out_size, void* d_ws, size_t ws_size,
                              hipStream_t stream){
    (void)in_sizes; (void)n_in; (void)out_size; (void)ws_size;
    const float* h   = (const float*)d_in[0];
    const int*   adj = (const int*)  d_in[1];
    const float* W   = (const float*)d_in[2];
    const float* a   = (const float*)d_in[3];
    float* out = (float*)d_out;

    char* ws = (char*)d_ws;
    uint16_t* WhbT  = (uint16_t*)(ws);                       // 8MB  [512][8192] bf16
    uint16_t* h_b   = (uint16_t*)(ws + (8u<<20));            // 8MB
    uint16_t* WT_b  = (uint16_t*)(ws + (16u<<20));           // 512KB
    uint32_t* packed= (uint32_t*)(ws + (17u<<20));           // 8MB
    float* fb   = (float*)(ws + (25u<<20));
    float* va1  = fb;            float* va2  = fb + 512;
    float* Tarr = fb + 1024;
    float* E1p  = Tarr + NN;     float* E1n  = E1p + NN;
    float* E2p  = E1n + NN;      float* E2n  = E2p + NN;
    float* rowP = E2n + NN;      float* rowN = rowP + NN;

    hipFuncSetAttribute((const void*)k_pack, hipFuncAttributeMaxDynamicSharedMemorySize, 65536);
    hipFuncSetAttribute((const void*)k_wh,   hipFuncAttributeMaxDynamicSharedMemorySize, 69632);
    hipFuncSetAttribute((const void*)k_main, hipFuncAttributeMaxDynamicSharedMemorySize, 135168);

    k_va  <<<64,   512, 0,      stream>>>(W, a, va1, va2);
    k_conv<<<2048, 256, 0,      stream>>>(h, W, h_b, WT_b);
    k_rows<<<2048, 256, 0,      stream>>>(h, va1, va2, Tarr, E1p, E1n, E2p, E2n);
    k_pack<<<2048, 256, 65536,  stream>>>(adj, Tarr, E1p, E1n, E2p, E2n, packed, rowP, rowN);
    k_wh  <<<256,  512, 69632,  stream>>>(h_b, WT_b, WhbT);
    k_main<<<256,  512, 135168, stream>>>(packed, WhbT, Tarr, rowP, rowN, E2p, E2n, out);
}

// Round 3
// 322.189 us; speedup vs baseline: 1.0070x; 1.0070x over previous
//
#include <hip/hip_runtime.h>
#include <stdint.h>
#include <stddef.h>

#define NN 8192
#define FD 512
#define ATTN_OFF (NN * FD)

typedef __attribute__((ext_vector_type(8))) short bf16x8;
typedef __attribute__((ext_vector_type(4))) float f32x4;
typedef __attribute__((ext_vector_type(4))) int i32x4;
typedef __attribute__((ext_vector_type(2))) uint32_t u32x2;
typedef __attribute__((ext_vector_type(4))) uint32_t u32x4;
typedef __attribute__((ext_vector_type(4))) uint16_t u16x4;

static __device__ __forceinline__ uint16_t f2bf(float x){
    union { float f; uint32_t u; } v; v.f = x;
    uint32_t r = v.u + 0x7FFFu + ((v.u >> 16) & 1u);
    return (uint16_t)(r >> 16);
}

#define GLDS(gp, lp) \
    __builtin_amdgcn_global_load_lds((__attribute__((address_space(1))) void*)(gp), \
                                     (__attribute__((address_space(3))) void*)(lp), 16, 0, 0)

// ---------------- u = W @ a1, v = W @ a2  (contract over OUT_F axis n) ---------------
__global__ void k_va(const float* __restrict__ W, const float* __restrict__ a,
                     float* __restrict__ va1, float* __restrict__ va2){
    const int lane = threadIdx.x & 63, wave = threadIdx.x >> 6;
    const int k = blockIdx.x*8 + wave;           // grid 64 x block 512 -> 512 rows
    const float* wr = W + (size_t)k*FD;
    float s1 = 0.f, s2 = 0.f;
    #pragma unroll
    for (int e = 0; e < 2; ++e){
        int c = e*256 + lane*4;
        f32x4 wv = *(const f32x4*)(wr + c);
        f32x4 x1 = *(const f32x4*)(a + c);
        f32x4 x2 = *(const f32x4*)(a + FD + c);
        s1 += wv[0]*x1[0] + wv[1]*x1[1] + wv[2]*x1[2] + wv[3]*x1[3];
        s2 += wv[0]*x2[0] + wv[1]*x2[1] + wv[2]*x2[2] + wv[3]*x2[3];
    }
    for (int off = 32; off; off >>= 1){ s1 += __shfl_down(s1, off); s2 += __shfl_down(s2, off); }
    if (lane == 0){ va1[k] = s1; va2[k] = s2; }
}

// ---------------- convert h -> bf16, W -> bf16 transposed ----------------------------
__global__ void k_conv(const float* __restrict__ h, const float* __restrict__ W,
                       uint16_t* __restrict__ h_b, uint16_t* __restrict__ WT_b){
    int idx = blockIdx.x * blockDim.x + threadIdx.x;
    int stride = gridDim.x * blockDim.x;
    for (int i = idx; i < NN*FD/4; i += stride){
        f32x4 v = ((const f32x4*)h)[i];
        u16x4 o;
        o[0] = f2bf(v[0]); o[1] = f2bf(v[1]); o[2] = f2bf(v[2]); o[3] = f2bf(v[3]);
        ((u16x4*)h_b)[i] = o;
    }
    for (int i = idx; i < FD*FD; i += stride){
        int n = i >> 9, k = i & 511;
        WT_b[i] = f2bf(W[(size_t)k*FD + n]);   // WT_b[n][k] = W[k][n]
    }
}

// ---------------- per-row s1,s2 and exp tables ---------------------------------------
__global__ void k_rows(const float* __restrict__ h, const float* __restrict__ va1,
                       const float* __restrict__ va2, float* __restrict__ Tarr,
                       float* __restrict__ E1p, float* __restrict__ E1n,
                       float* __restrict__ E2p, float* __restrict__ E2n){
    const int lane = threadIdx.x & 63, wave = threadIdx.x >> 6;
    const int row = blockIdx.x*4 + wave;
    const float* hr = h + (size_t)row * FD;
    float s1 = 0.f, s2 = 0.f;
    #pragma unroll
    for (int e = 0; e < 2; ++e){
        int c = e*256 + lane*4;
        f32x4 hv = *(const f32x4*)(hr + c);
        f32x4 x1 = *(const f32x4*)(va1 + c);
        f32x4 x2 = *(const f32x4*)(va2 + c);
        s1 += hv[0]*x1[0] + hv[1]*x1[1] + hv[2]*x1[2] + hv[3]*x1[3];
        s2 += hv[0]*x2[0] + hv[1]*x2[1] + hv[2]*x2[2] + hv[3]*x2[3];
    }
    for (int off = 32; off; off >>= 1){ s1 += __shfl_down(s1, off); s2 += __shfl_down(s2, off); }
    if (lane == 0){
        Tarr[row] = expf(-s1);        // threshold: x>0  <=>  E2p[j] > T[i]
        E1p[row]  = expf(s1);
        E1n[row]  = expf(0.2f*s1);
        E2p[row]  = expf(s2);
        E2n[row]  = expf(0.2f*s2);
    }
}

// ---------------- pass over adj: softmax denominators + bit-pack ---------------------
// packed word layout: word w (of 256/row), bit b: j = (w>>6)*2048 + (b>>2)*256 + (w&63)*4 + (b&3)
__global__ void k_pack(const int* __restrict__ adj, const float* __restrict__ Tarr,
                       const float* __restrict__ E1p, const float* __restrict__ E1n,
                       const float* __restrict__ E2p, const float* __restrict__ E2n,
                       uint32_t* __restrict__ packed, float* __restrict__ rowP,
                       float* __restrict__ rowN){
    extern __shared__ char smem[];
    float* P_s = (float*)smem;            // 32KB  E2p
    float* Q_s = (float*)(smem + 32768);  // 32KB  E2n
    const int tid = threadIdx.x, lane = tid & 63, wave = tid >> 6;
    for (int t = tid; t < NN/4; t += 256){
        ((f32x4*)P_s)[t] = ((const f32x4*)E2p)[t];
        ((f32x4*)Q_s)[t] = ((const f32x4*)E2n)[t];
    }
    __syncthreads();
    const int row = blockIdx.x*4 + wave;
    const float T_i = Tarr[row];
    const int* arow = adj + (size_t)row * NN;
    float Ap = 0.f, An = 0.f;
    #pragma unroll
    for (int g = 0; g < 4; ++g){
        uint32_t word = 0;
        #pragma unroll
        for (int e = 0; e < 8; ++e){
            int j0 = g*2048 + e*256 + lane*4;
            i32x4 av = *(const i32x4*)(arow + j0);
            f32x4 p = ((const f32x4*)P_s)[j0 >> 2];
            f32x4 q = ((const f32x4*)Q_s)[j0 >> 2];
            #pragma unroll
            for (int c = 0; c < 4; ++c){
                if (av[c] != 0){
                    if (p[c] > T_i) Ap += p[c]; else An += q[c];
                    word |= (1u << (e*4 + c));
                }
            }
        }
        packed[(size_t)row*256 + g*64 + lane] = word;
    }
    for (int off = 32; off; off >>= 1){
        Ap += __shfl_down(Ap, off);
        An += __shfl_down(An, off);
    }
    if (lane == 0){
        float e1p = E1p[row], e1n = E1n[row];
        float inv = 1.0f / (e1p*Ap + e1n*An);
        rowP[row] = e1p * inv;
        rowN[row] = e1n * inv;
    }
}

// ---------------- shared MFMA inner tile (A:[32][64] swz, B:[512][64] swz) -----------
static __device__ __forceinline__ void mfma_tile(const char* A_base, const char* B_base,
                                                 int wave, int lane, f32x4 acc[2][4]){
    #pragma unroll
    for (int kk = 0; kk < 2; ++kk){
        bf16x8 afr[2], bfr[4];
        #pragma unroll
        for (int t = 0; t < 2; ++t){
            int rowl = t*16 + (lane & 15);
            int slot = (kk*4 + (lane >> 4)) ^ (rowl & 7);
            afr[t] = *(const bf16x8*)(A_base + rowl*128 + slot*16);
        }
        #pragma unroll
        for (int n = 0; n < 4; ++n){
            int nl = wave*64 + n*16 + (lane & 15);
            int slot = (kk*4 + (lane >> 4)) ^ (nl & 7);
            bfr[n] = *(const bf16x8*)(B_base + nl*128 + slot*16);
        }
        #pragma unroll
        for (int t = 0; t < 2; ++t)
            #pragma unroll
            for (int n = 0; n < 4; ++n)
                acc[t][n] = __builtin_amdgcn_mfma_f32_16x16x32_bf16(afr[t], bfr[n], acc[t][n], 0, 0, 0);
    }
}

// ---------------- Wh GEMM: WhbT[n][m] = bf16( h[m,:] @ W[:,n] ) ----------------------
__global__ __launch_bounds__(512) void k_wh(const uint16_t* __restrict__ h_b,
                                            const uint16_t* __restrict__ WT_b,
                                            uint16_t* __restrict__ WhbT){
    extern __shared__ char smem[];
    char* A_base = smem;            // 4KB  [32][64] bf16 swz
    char* B_base = smem + 4096;     // 64KB [512][64] bf16 swz; epilogue reuses as Ts
    const int tid = threadIdx.x, wave = tid >> 6, lane = tid & 63;
    const int mb0 = blockIdx.x * 32;
    f32x4 acc[2][4];
    #pragma unroll
    for (int t = 0; t < 2; ++t)
        #pragma unroll
        for (int n = 0; n < 4; ++n) acc[t][n] = (f32x4){0.f,0.f,0.f,0.f};

    for (int k0 = 0; k0 < FD; k0 += 64){
        if (wave < 4){
            int m = wave*8 + (lane >> 3);
            int chunk = (lane & 7) ^ (m & 7);
            GLDS(h_b + (size_t)(mb0 + m)*FD + k0 + chunk*8, A_base + wave*1024);
        }
        #pragma unroll
        for (int r = 0; r < 8; ++r){
            int nn = wave*64 + r*8 + (lane >> 3);
            int chunk = (lane & 7) ^ (nn & 7);
            GLDS(WT_b + (size_t)nn*FD + k0 + chunk*8, B_base + (wave*64 + r*8)*128);
        }
        __syncthreads();
        mfma_tile(A_base, B_base, wave, lane, acc);
        __syncthreads();
    }
    // transpose via LDS: Ts[n][m], row stride 40 shorts (80B, 16B aligned)
    uint16_t* Ts = (uint16_t*)B_base;
    #pragma unroll
    for (int t = 0; t < 2; ++t)
        #pragma unroll
        for (int n = 0; n < 4; ++n)
            #pragma unroll
            for (int r = 0; r < 4; ++r){
                int nl = wave*64 + n*16 + (lane & 15);
                int m  = t*16 + (lane >> 4)*4 + r;
                Ts[nl*40 + m] = f2bf(acc[t][n][r]);
            }
    __syncthreads();
    {
        int n = tid;   // 512 rows
        const u32x4* src = (const u32x4*)(Ts + n*40);
        u32x4* dst = (u32x4*)(WhbT + (size_t)n*NN + mb0);
        #pragma unroll
        for (int r = 0; r < 4; ++r) dst[r] = src[r];
    }
}

// ---------------- fused: attention write + attn @ Wh + ELU ---------------------------
// Double-buffered A/B, one raw barrier per k-step, attn store never drained.
__global__ __launch_bounds__(512) void k_main(const uint32_t* __restrict__ packed,
                                              const uint16_t* __restrict__ WhbT,
                                              const float* __restrict__ Tarr,
                                              const float* __restrict__ rowP,
                                              const float* __restrict__ rowN,
                                              const float* __restrict__ E2p,
                                              const float* __restrict__ E2n,
                                              float* __restrict__ out){
    extern __shared__ char smem[];
    char* A_lds = smem;             // 2 x 4KB  [32][64] bf16 swz
    char* B_lds = smem + 8192;      // 2 x 64KB [512][64] bf16 swz   (total 136KB)

    const int tid = threadIdx.x;
    const int il = tid >> 4, jg = tid & 15;
    const int wave = tid >> 6, lane = tid & 63;
    const int row = blockIdx.x * 32 + il;

    const float T_i = Tarr[row], rP = rowP[row], rN = rowN[row];
    const uint32_t* packrow = packed + (size_t)row * 256;
    float* attn_out = out + ATTN_OFF + (size_t)row * NN;

    f32x4 acc[2][4];
    #pragma unroll
    for (int t = 0; t < 2; ++t)
        #pragma unroll
        for (int n = 0; n < 4; ++n) acc[t][n] = (f32x4){0.f,0.f,0.f,0.f};

    auto STAGE_B = [&](char* Bdst, int k0){
        char* Bw = Bdst + wave*8192;
        #pragma unroll
        for (int r = 0; r < 8; ++r){
            int nn = wave*64 + r*8 + (lane >> 3);
            int chunk = (lane & 7) ^ (nn & 7);
            GLDS(WhbT + (size_t)nn*NN + k0 + chunk*8, Bw + r*1024);
        }
    };
    auto GEN_A = [&](char* Adst, int k0){
        uint32_t word = packrow[(k0 >> 11)*64 + ((k0 & 255) >> 2) + jg];
        int shift = ((k0 >> 8) & 7) * 4;
        f32x4 p = *(const f32x4*)(E2p + k0 + jg*4);
        f32x4 q = *(const f32x4*)(E2n + k0 + jg*4);
        float va[4];
        #pragma unroll
        for (int c = 0; c < 4; ++c){
            float val = (p[c] > T_i) ? rP * p[c] : rN * q[c];
            va[c] = ((word >> (shift + c)) & 1u) ? val : 0.f;
        }
        f32x4 st; st[0]=va[0]; st[1]=va[1]; st[2]=va[2]; st[3]=va[3];
        *(f32x4*)(attn_out + k0 + jg*4) = st;
        uint32_t lo = ((uint32_t)f2bf(va[1]) << 16) | f2bf(va[0]);
        uint32_t hi = ((uint32_t)f2bf(va[3]) << 16) | f2bf(va[2]);
        u32x2 pr; pr[0] = lo; pr[1] = hi;
        int abyte = il*128 + ((((jg >> 1) ^ (il & 7)) << 4) | ((jg & 1) << 3));
        *(u32x2*)(Adst + abyte) = pr;
    };

    // prologue: stage step 0 into buf0
    STAGE_B(B_lds, 0);
    __builtin_amdgcn_sched_barrier(0);
    GEN_A(A_lds, 0);
    asm volatile("s_waitcnt vmcnt(1) lgkmcnt(0)" ::: "memory");
    __builtin_amdgcn_s_barrier();

    for (int t = 0; t < 128; ++t){
        const int cur = t & 1;
        char* Ac = A_lds + cur*4096;
        char* Bc = B_lds + cur*65536;
        if (t < 127){
            // issue next-tile staging first: latency hides under MFMA below
            STAGE_B(B_lds + (cur^1)*65536, (t+1)*64);
            __builtin_amdgcn_sched_barrier(0);
        }
        __builtin_amdgcn_s_setprio(1);
        mfma_tile(Ac, Bc, wave, lane, acc);
        __builtin_amdgcn_s_setprio(0);
        if (t < 127){
            GEN_A(A_lds + (cur^1)*4096, (t+1)*64);
            // vmcnt(1): allow this step's attn store to stay in flight; the
            // GEN_A table loads (issued after the 8 GLDS, order pinned by
            // sched_barrier) were consumed above, so in-order retirement
            // guarantees the GLDS have landed in LDS.
            asm volatile("s_waitcnt vmcnt(1) lgkmcnt(0)" ::: "memory");
            __builtin_amdgcn_s_barrier();
        }
    }
    // epilogue: ELU + store h_prime
    #pragma unroll
    for (int t = 0; t < 2; ++t)
        #pragma unroll
        for (int n = 0; n < 4; ++n)
            #pragma unroll
            for (int r = 0; r < 4; ++r){
                int m   = blockIdx.x*32 + t*16 + (lane >> 4)*4 + r;
                int col = wave*64 + n*16 + (lane & 15);
                float x = acc[t][n][r];
                out[(size_t)m*FD + col] = (x > 0.f) ? x : expm1f(x);
            }
}

extern "C" void kernel_launch(void* const* d_in, const int* in_sizes, int n_in,
                              void* d_out, int out_size, void* d_ws, size_t ws_size,
                              hipStream_t stream){
    (void)in_sizes; (void)n_in; (void)out_size; (void)ws_size;
    const float* h   = (const float*)d_in[0];
    const int*   adj = (const int*)  d_in[1];
    const float* W   = (const float*)d_in[2];
    const float* a   = (const float*)d_in[3];
    float* out = (float*)d_out;

    char* ws = (char*)d_ws;
    uint16_t* WhbT  = (uint16_t*)(ws);                       // 8MB  [512][8192] bf16
    uint16_t* h_b   = (uint16_t*)(ws + (8u<<20));            // 8MB
    uint16_t* WT_b  = (uint16_t*)(ws + (16u<<20));           // 512KB
    uint32_t* packed= (uint32_t*)(ws + (17u<<20));           // 8MB
    float* fb   = (float*)(ws + (25u<<20));
    float* va1  = fb;            float* va2  = fb + 512;
    float* Tarr = fb + 1024;
    float* E1p  = Tarr + NN;     float* E1n  = E1p + NN;
    float* E2p  = E1n + NN;      float* E2n  = E2p + NN;
    float* rowP = E2n + NN;      float* rowN = rowP + NN;

    hipFuncSetAttribute((const void*)k_pack, hipFuncAttributeMaxDynamicSharedMemorySize, 65536);
    hipFuncSetAttribute((const void*)k_wh,   hipFuncAttributeMaxDynamicSharedMemorySize, 69632);
    hipFuncSetAttribute((const void*)k_main, hipFuncAttributeMaxDynamicSharedMemorySize, 139264);

    k_va  <<<64,   512, 0,      stream>>>(W, a, va1, va2);
    k_conv<<<2048, 256, 0,      stream>>>(h, W, h_b, WT_b);
    k_rows<<<2048, 256, 0,      stream>>>(h, va1, va2, Tarr, E1p, E1n, E2p, E2n);
    k_pack<<<2048, 256, 65536,  stream>>>(adj, Tarr, E1p, E1n, E2p, E2n, packed, rowP, rowN);
    k_wh  <<<256,  512, 69632,  stream>>>(h_b, WT_b, WhbT);
    k_main<<<256,  512, 139264, stream>>>(packed, WhbT, Tarr, rowP, rowN, E2p, E2n, out);
}

// Round 4
// 270.554 us; speedup vs baseline: 1.1992x; 1.1909x over previous
//
#include <hip/hip_runtime.h>
#include <stdint.h>
#include <stddef.h>

#define NN 8192
#define FD 512
#define ATTN_OFF (NN * FD)

typedef __attribute__((ext_vector_type(8))) short bf16x8;
typedef __attribute__((ext_vector_type(4))) float f32x4;
typedef __attribute__((ext_vector_type(4))) int i32x4;
typedef __attribute__((ext_vector_type(2))) uint32_t u32x2;
typedef __attribute__((ext_vector_type(4))) uint32_t u32x4;
typedef __attribute__((ext_vector_type(4))) uint16_t u16x4;

static __device__ __forceinline__ uint16_t f2bf(float x){
    union { float f; uint32_t u; } v; v.f = x;
    uint32_t r = v.u + 0x7FFFu + ((v.u >> 16) & 1u);
    return (uint16_t)(r >> 16);
}

#define GLDS(gp, lp) \
    __builtin_amdgcn_global_load_lds((__attribute__((address_space(1))) void*)(gp), \
                                     (__attribute__((address_space(3))) void*)(lp), 16, 0, 0)

// ---------------- u = W @ a1, v = W @ a2  (contract over OUT_F axis n) ---------------
__global__ void k_va(const float* __restrict__ W, const float* __restrict__ a,
                     float* __restrict__ va1, float* __restrict__ va2){
    const int lane = threadIdx.x & 63, wave = threadIdx.x >> 6;
    const int k = blockIdx.x*8 + wave;           // grid 64 x block 512 -> 512 rows
    const float* wr = W + (size_t)k*FD;
    float s1 = 0.f, s2 = 0.f;
    #pragma unroll
    for (int e = 0; e < 2; ++e){
        int c = e*256 + lane*4;
        f32x4 wv = *(const f32x4*)(wr + c);
        f32x4 x1 = *(const f32x4*)(a + c);
        f32x4 x2 = *(const f32x4*)(a + FD + c);
        s1 += wv[0]*x1[0] + wv[1]*x1[1] + wv[2]*x1[2] + wv[3]*x1[3];
        s2 += wv[0]*x2[0] + wv[1]*x2[1] + wv[2]*x2[2] + wv[3]*x2[3];
    }
    for (int off = 32; off; off >>= 1){ s1 += __shfl_down(s1, off); s2 += __shfl_down(s2, off); }
    if (lane == 0){ va1[k] = s1; va2[k] = s2; }
}

// ---------------- convert h -> bf16, W -> bf16 transposed ----------------------------
__global__ void k_conv(const float* __restrict__ h, const float* __restrict__ W,
                       uint16_t* __restrict__ h_b, uint16_t* __restrict__ WT_b){
    int idx = blockIdx.x * blockDim.x + threadIdx.x;
    int stride = gridDim.x * blockDim.x;
    for (int i = idx; i < NN*FD/4; i += stride){
        f32x4 v = ((const f32x4*)h)[i];
        u16x4 o;
        o[0] = f2bf(v[0]); o[1] = f2bf(v[1]); o[2] = f2bf(v[2]); o[3] = f2bf(v[3]);
        ((u16x4*)h_b)[i] = o;
    }
    for (int i = idx; i < FD*FD; i += stride){
        int n = i >> 9, k = i & 511;
        WT_b[i] = f2bf(W[(size_t)k*FD + n]);   // WT_b[n][k] = W[k][n]
    }
}

// ---------------- per-row s1,s2 and exp tables ---------------------------------------
__global__ void k_rows(const float* __restrict__ h, const float* __restrict__ va1,
                       const float* __restrict__ va2, float* __restrict__ Tarr,
                       float* __restrict__ E1p, float* __restrict__ E1n,
                       float* __restrict__ E2p, float* __restrict__ E2n){
    const int lane = threadIdx.x & 63, wave = threadIdx.x >> 6;
    const int row = blockIdx.x*4 + wave;
    const float* hr = h + (size_t)row * FD;
    float s1 = 0.f, s2 = 0.f;
    #pragma unroll
    for (int e = 0; e < 2; ++e){
        int c = e*256 + lane*4;
        f32x4 hv = *(const f32x4*)(hr + c);
        f32x4 x1 = *(const f32x4*)(va1 + c);
        f32x4 x2 = *(const f32x4*)(va2 + c);
        s1 += hv[0]*x1[0] + hv[1]*x1[1] + hv[2]*x1[2] + hv[3]*x1[3];
        s2 += hv[0]*x2[0] + hv[1]*x2[1] + hv[2]*x2[2] + hv[3]*x2[3];
    }
    for (int off = 32; off; off >>= 1){ s1 += __shfl_down(s1, off); s2 += __shfl_down(s2, off); }
    if (lane == 0){
        Tarr[row] = expf(-s1);        // threshold: x>0  <=>  E2p[j] > T[i]
        E1p[row]  = expf(s1);
        E1n[row]  = expf(0.2f*s1);
        E2p[row]  = expf(s2);
        E2n[row]  = expf(0.2f*s2);
    }
}

// ---------------- pass over adj: softmax denominators + bit-pack ---------------------
// packed word layout: word w (of 256/row), bit b: j = (w>>6)*2048 + (b>>2)*256 + (w&63)*4 + (b&3)
__global__ void k_pack(const int* __restrict__ adj, const float* __restrict__ Tarr,
                       const float* __restrict__ E1p, const float* __restrict__ E1n,
                       const float* __restrict__ E2p, const float* __restrict__ E2n,
                       uint32_t* __restrict__ packed, float* __restrict__ rowP,
                       float* __restrict__ rowN){
    extern __shared__ char smem[];
    float* P_s = (float*)smem;            // 32KB  E2p
    float* Q_s = (float*)(smem + 32768);  // 32KB  E2n
    const int tid = threadIdx.x, lane = tid & 63, wave = tid >> 6;
    for (int t = tid; t < NN/4; t += 256){
        ((f32x4*)P_s)[t] = ((const f32x4*)E2p)[t];
        ((f32x4*)Q_s)[t] = ((const f32x4*)E2n)[t];
    }
    __syncthreads();
    const int row = blockIdx.x*4 + wave;
    const float T_i = Tarr[row];
    const int* arow = adj + (size_t)row * NN;
    float Ap = 0.f, An = 0.f;
    #pragma unroll
    for (int g = 0; g < 4; ++g){
        uint32_t word = 0;
        #pragma unroll
        for (int e = 0; e < 8; ++e){
            int j0 = g*2048 + e*256 + lane*4;
            i32x4 av = *(const i32x4*)(arow + j0);
            f32x4 p = ((const f32x4*)P_s)[j0 >> 2];
            f32x4 q = ((const f32x4*)Q_s)[j0 >> 2];
            #pragma unroll
            for (int c = 0; c < 4; ++c){
                if (av[c] != 0){
                    if (p[c] > T_i) Ap += p[c]; else An += q[c];
                    word |= (1u << (e*4 + c));
                }
            }
        }
        packed[(size_t)row*256 + g*64 + lane] = word;
    }
    for (int off = 32; off; off >>= 1){
        Ap += __shfl_down(Ap, off);
        An += __shfl_down(An, off);
    }
    if (lane == 0){
        float e1p = E1p[row], e1n = E1n[row];
        float inv = 1.0f / (e1p*Ap + e1n*An);
        rowP[row] = e1p * inv;
        rowN[row] = e1n * inv;
    }
}

// ---------------- MFMA inner tile, M=32 variant for k_wh -----------------------------
static __device__ __forceinline__ void mfma_tile(const char* A_base, const char* B_base,
                                                 int wave, int lane, f32x4 acc[2][4]){
    #pragma unroll
    for (int kk = 0; kk < 2; ++kk){
        bf16x8 afr[2], bfr[4];
        #pragma unroll
        for (int t = 0; t < 2; ++t){
            int rowl = t*16 + (lane & 15);
            int slot = (kk*4 + (lane >> 4)) ^ (rowl & 7);
            afr[t] = *(const bf16x8*)(A_base + rowl*128 + slot*16);
        }
        #pragma unroll
        for (int n = 0; n < 4; ++n){
            int nl = wave*64 + n*16 + (lane & 15);
            int slot = (kk*4 + (lane >> 4)) ^ (nl & 7);
            bfr[n] = *(const bf16x8*)(B_base + nl*128 + slot*16);
        }
        #pragma unroll
        for (int t = 0; t < 2; ++t)
            #pragma unroll
            for (int n = 0; n < 4; ++n)
                acc[t][n] = __builtin_amdgcn_mfma_f32_16x16x32_bf16(afr[t], bfr[n], acc[t][n], 0, 0, 0);
    }
}

// ---------------- MFMA inner tile, M=128 variant for k_main --------------------------
static __device__ __forceinline__ void mfma_tile128(const char* A_base, const char* B_base,
                                                    int wave, int lane, f32x4 acc[8][4]){
    #pragma unroll
    for (int kk = 0; kk < 2; ++kk){
        bf16x8 afr[8], bfr[4];
        #pragma unroll
        for (int mi = 0; mi < 8; ++mi){
            int rowl = mi*16 + (lane & 15);
            int slot = (kk*4 + (lane >> 4)) ^ (rowl & 7);
            afr[mi] = *(const bf16x8*)(A_base + rowl*128 + slot*16);
        }
        #pragma unroll
        for (int n = 0; n < 4; ++n){
            int nl = wave*64 + n*16 + (lane & 15);
            int slot = (kk*4 + (lane >> 4)) ^ (nl & 7);
            bfr[n] = *(const bf16x8*)(B_base + nl*128 + slot*16);
        }
        #pragma unroll
        for (int mi = 0; mi < 8; ++mi)
            #pragma unroll
            for (int n = 0; n < 4; ++n)
                acc[mi][n] = __builtin_amdgcn_mfma_f32_16x16x32_bf16(afr[mi], bfr[n], acc[mi][n], 0, 0, 0);
    }
}

// ---------------- Wh GEMM: WhbT[n][m] = bf16( h[m,:] @ W[:,n] ) ----------------------
__global__ __launch_bounds__(512) void k_wh(const uint16_t* __restrict__ h_b,
                                            const uint16_t* __restrict__ WT_b,
                                            uint16_t* __restrict__ WhbT){
    extern __shared__ char smem[];
    char* A_base = smem;            // 4KB  [32][64] bf16 swz
    char* B_base = smem + 4096;     // 64KB [512][64] bf16 swz; epilogue reuses as Ts
    const int tid = threadIdx.x, wave = tid >> 6, lane = tid & 63;
    const int mb0 = blockIdx.x * 32;
    f32x4 acc[2][4];
    #pragma unroll
    for (int t = 0; t < 2; ++t)
        #pragma unroll
        for (int n = 0; n < 4; ++n) acc[t][n] = (f32x4){0.f,0.f,0.f,0.f};

    for (int k0 = 0; k0 < FD; k0 += 64){
        if (wave < 4){
            int m = wave*8 + (lane >> 3);
            int chunk = (lane & 7) ^ (m & 7);
            GLDS(h_b + (size_t)(mb0 + m)*FD + k0 + chunk*8, A_base + wave*1024);
        }
        #pragma unroll
        for (int r = 0; r < 8; ++r){
            int nn = wave*64 + r*8 + (lane >> 3);
            int chunk = (lane & 7) ^ (nn & 7);
            GLDS(WT_b + (size_t)nn*FD + k0 + chunk*8, B_base + (wave*64 + r*8)*128);
        }
        __syncthreads();
        mfma_tile(A_base, B_base, wave, lane, acc);
        __syncthreads();
    }
    // transpose via LDS: Ts[n][m], row stride 40 shorts (80B, 16B aligned)
    uint16_t* Ts = (uint16_t*)B_base;
    #pragma unroll
    for (int t = 0; t < 2; ++t)
        #pragma unroll
        for (int n = 0; n < 4; ++n)
            #pragma unroll
            for (int r = 0; r < 4; ++r){
                int nl = wave*64 + n*16 + (lane & 15);
                int m  = t*16 + (lane >> 4)*4 + r;
                Ts[nl*40 + m] = f2bf(acc[t][n][r]);
            }
    __syncthreads();
    {
        int n = tid;   // 512 rows
        const u32x4* src = (const u32x4*)(Ts + n*40);
        u32x4* dst = (u32x4*)(WhbT + (size_t)n*NN + mb0);
        #pragma unroll
        for (int r = 0; r < 4; ++r) dst[r] = src[r];
    }
}

// ---------------- fused: attention write + attn @ Wh (partial over k-slice) ----------
// grid 256 = 64 m-blocks x 4 k-splits; ksplit pinned per XCD pair for L2 residency.
// Block: rows [m*128, m*128+128), k in [ks*2048, ks*2048+2048), 32 steps of 64.
__global__ __launch_bounds__(512) void k_main(const uint32_t* __restrict__ packed,
                                              const uint16_t* __restrict__ WhbT,
                                              const float* __restrict__ Tarr,
                                              const float* __restrict__ rowP,
                                              const float* __restrict__ rowN,
                                              const float* __restrict__ E2p,
                                              const float* __restrict__ E2n,
                                              float* __restrict__ hp_part,
                                              float* __restrict__ out){
    extern __shared__ char smem[];
    char* A_base = smem;            // 16KB [128][64] bf16 swz (single buffer)
    char* B_lds  = smem + 16384;    // 2 x 64KB [512][64] bf16 swz  (total 144KB)

    const int tid = threadIdx.x;
    const int il = tid >> 4, jg = tid & 15;        // il in [0,32): row group; jg: col group
    const int wave = tid >> 6, lane = tid & 63;

    const int bi = blockIdx.x;
    const int ks = (bi & 7) >> 1;                  // k-split, constant per XCD pair
    const int m_idx = (bi >> 3)*2 + (bi & 1);      // [0,64)
    const int row0 = m_idx * 128;
    const int kbase = ks * 2048;

    // per-thread row parameters for rows {row0+il, +32, +64, +96}
    float Ts_[4], rPs[4], rNs[4];
    #pragma unroll
    for (int s = 0; s < 4; ++s){
        int gr = row0 + il + 32*s;
        Ts_[s] = Tarr[gr]; rPs[s] = rowP[gr]; rNs[s] = rowN[gr];
    }

    f32x4 acc[8][4];
    #pragma unroll
    for (int mi = 0; mi < 8; ++mi)
        #pragma unroll
        for (int n = 0; n < 4; ++n) acc[mi][n] = (f32x4){0.f,0.f,0.f,0.f};

    auto STAGE_B = [&](char* Bdst, int k0){
        char* Bw = Bdst + wave*8192;
        #pragma unroll
        for (int r = 0; r < 8; ++r){
            int nn = wave*64 + r*8 + (lane >> 3);
            int chunk = (lane & 7) ^ (nn & 7);
            GLDS(WhbT + (size_t)nn*NN + k0 + chunk*8, Bw + r*1024);
        }
    };
    auto GEN_A = [&](int k0){
        f32x4 p = *(const f32x4*)(E2p + k0 + jg*4);
        f32x4 q = *(const f32x4*)(E2n + k0 + jg*4);
        int widx  = (k0 >> 11)*64 + ((k0 & 255) >> 2) + jg;
        int shift = ((k0 >> 8) & 7) * 4;
        #pragma unroll
        for (int s = 0; s < 4; ++s){
            int r = il + 32*s;
            int grow = row0 + r;
            uint32_t word = packed[(size_t)grow*256 + widx];
            float va[4];
            #pragma unroll
            for (int c = 0; c < 4; ++c){
                float val = (p[c] > Ts_[s]) ? rPs[s]*p[c] : rNs[s]*q[c];
                va[c] = ((word >> (shift + c)) & 1u) ? val : 0.f;
            }
            f32x4 st; st[0]=va[0]; st[1]=va[1]; st[2]=va[2]; st[3]=va[3];
            *(f32x4*)(out + ATTN_OFF + (size_t)grow*NN + k0 + jg*4) = st;
            uint32_t lo = ((uint32_t)f2bf(va[1]) << 16) | f2bf(va[0]);
            uint32_t hi = ((uint32_t)f2bf(va[3]) << 16) | f2bf(va[2]);
            u32x2 pr; pr[0] = lo; pr[1] = hi;
            int abyte = r*128 + ((((jg >> 1) ^ (r & 7)) << 4) | ((jg & 1) << 3));
            *(u32x2*)(A_base + abyte) = pr;
        }
    };

    // prologue: stage B(k0=kbase) into buf0, generate A(kbase)
    STAGE_B(B_lds, kbase);
    __builtin_amdgcn_sched_barrier(0);
    GEN_A(kbase);
    // vmcnt(4): the 4 attn stores may remain in flight; everything earlier
    // (8 GLDS + table/pack loads) has retired (in-order vmcnt).
    asm volatile("s_waitcnt vmcnt(4) lgkmcnt(0)" ::: "memory");
    __builtin_amdgcn_s_barrier();

    for (int t = 0; t < 32; ++t){
        const int cur = t & 1;
        if (t < 31){
            STAGE_B(B_lds + (cur^1)*65536, kbase + (t+1)*64);
            __builtin_amdgcn_sched_barrier(0);
        }
        __builtin_amdgcn_s_setprio(1);
        mfma_tile128(A_base, B_lds + cur*65536, wave, lane, acc);
        __builtin_amdgcn_s_setprio(0);
        __builtin_amdgcn_s_barrier();       // all waves done reading A + B[cur]
        if (t < 31){
            GEN_A(kbase + (t+1)*64);        // overwrite A for next step
            asm volatile("s_waitcnt vmcnt(4) lgkmcnt(0)" ::: "memory");
            __builtin_amdgcn_s_barrier();
        }
    }
    // epilogue: store f32 partial (no ELU yet)
    float* hp = hp_part + (size_t)ks * NN * FD;
    #pragma unroll
    for (int mi = 0; mi < 8; ++mi)
        #pragma unroll
        for (int n = 0; n < 4; ++n)
            #pragma unroll
            for (int r = 0; r < 4; ++r){
                int m   = row0 + mi*16 + (lane >> 4)*4 + r;
                int col = wave*64 + n*16 + (lane & 15);
                hp[(size_t)m*FD + col] = acc[mi][n][r];
            }
}

// ---------------- reduce 4 k-split partials + ELU ------------------------------------
__global__ __launch_bounds__(512) void k_red(const float* __restrict__ hp,
                                             float* __restrict__ out){
    const size_t i = (size_t)blockIdx.x * 512 + threadIdx.x;   // f32x4 index
    const size_t off = (size_t)NN * FD / 4;
    f32x4 a = ((const f32x4*)hp)[i];
    f32x4 b = ((const f32x4*)hp)[i + off];
    f32x4 c = ((const f32x4*)hp)[i + off*2];
    f32x4 d = ((const f32x4*)hp)[i + off*3];
    f32x4 s;
    #pragma unroll
    for (int e = 0; e < 4; ++e){
        float x = (a[e] + b[e]) + (c[e] + d[e]);
        s[e] = (x > 0.f) ? x : expm1f(x);
    }
    ((f32x4*)out)[i] = s;
}

extern "C" void kernel_launch(void* const* d_in, const int* in_sizes, int n_in,
                              void* d_out, int out_size, void* d_ws, size_t ws_size,
                              hipStream_t stream){
    (void)in_sizes; (void)n_in; (void)out_size; (void)ws_size;
    const float* h   = (const float*)d_in[0];
    const int*   adj = (const int*)  d_in[1];
    const float* W   = (const float*)d_in[2];
    const float* a   = (const float*)d_in[3];
    float* out = (float*)d_out;

    char* ws = (char*)d_ws;
    uint16_t* WhbT  = (uint16_t*)(ws);                       // 8MB  [512][8192] bf16
    uint16_t* h_b   = (uint16_t*)(ws + (8u<<20));            // 8MB
    uint16_t* WT_b  = (uint16_t*)(ws + (16u<<20));           // 512KB
    uint32_t* packed= (uint32_t*)(ws + (17u<<20));           // 8MB
    float* fb   = (float*)(ws + (25u<<20));                  // ~300KB of small arrays
    float* va1  = fb;            float* va2  = fb + 512;
    float* Tarr = fb + 1024;
    float* E1p  = Tarr + NN;     float* E1n  = E1p + NN;
    float* E2p  = E1n + NN;      float* E2n  = E2p + NN;
    float* rowP = E2n + NN;      float* rowN = rowP + NN;
    float* hp_part = (float*)(ws + (32u<<20));               // 64MB: 4 x [8192][512] f32

    hipFuncSetAttribute((const void*)k_pack, hipFuncAttributeMaxDynamicSharedMemorySize, 65536);
    hipFuncSetAttribute((const void*)k_wh,   hipFuncAttributeMaxDynamicSharedMemorySize, 69632);
    hipFuncSetAttribute((const void*)k_main, hipFuncAttributeMaxDynamicSharedMemorySize, 147456);

    k_va  <<<64,   512, 0,      stream>>>(W, a, va1, va2);
    k_conv<<<2048, 256, 0,      stream>>>(h, W, h_b, WT_b);
    k_rows<<<2048, 256, 0,      stream>>>(h, va1, va2, Tarr, E1p, E1n, E2p, E2n);
    k_pack<<<2048, 256, 65536,  stream>>>(adj, Tarr, E1p, E1n, E2p, E2n, packed, rowP, rowN);
    k_wh  <<<256,  512, 69632,  stream>>>(h_b, WT_b, WhbT);
    k_main<<<256,  512, 147456, stream>>>(packed, WhbT, Tarr, rowP, rowN, E2p, E2n, hp_part, out);
    k_red <<<2048, 512, 0,      stream>>>(hp_part, out);
}